// Round 5
// baseline (77.020 us; speedup 1.0000x reference)
//
#include <hip/hip_runtime.h>
#include <math.h>

#define B_   128
#define H_   192
#define W_   192
#define NC_  5
#define HW_  (H_*W_)
#define NPTS 9
#define EPS_ 1e-8f
#define CHUNK 8    // combos per warp-kernel block (one transform per kernel)

typedef int   vint4   __attribute__((ext_vector_type(4)));
typedef float vfloat4 __attribute__((ext_vector_type(4)));

struct LinvT { float m[12][NPTS]; };

// ---------------- Kernel 1: mask -> per-pixel fg count (bg == (fg==0)) ---------------
__global__ __launch_bounds__(256) void code_kernel(
    const int* __restrict__ masks, unsigned int* __restrict__ code)
{
    int idx = blockIdx.x * 256 + threadIdx.x;      // one thread per 4 pixels
    const int total4 = B_ * HW_ / 4;
    if (idx >= total4) return;
    int b  = idx / (HW_ / 4);
    int p4 = (idx - b * (HW_ / 4)) * 4;

    int s0 = 0, s1 = 0, s2 = 0, s3 = 0;
    #pragma unroll
    for (int c = 0; c < NC_; ++c) {
        const vint4* mp = reinterpret_cast<const vint4*>(masks + ((size_t)b * NC_ + c) * HW_ + p4);
        vint4 mv = __builtin_nontemporal_load(mp);
        s0 += mv[0]; s1 += mv[1]; s2 += mv[2]; s3 += mv[3];
    }
    unsigned int packed = (unsigned)s0 | ((unsigned)s1 << 8) |
                          ((unsigned)s2 << 16) | ((unsigned)s3 << 24);
    code[((size_t)b * HW_ + p4) >> 2] = packed;
}

// ---------------- Kernel 2: point_elasticity + TPS solve fused (per-batch block) ------
__global__ void prep_kernel(const int* __restrict__ masks,
                            const float* __restrict__ ng,
                            const float* __restrict__ nl,
                            LinvT Linv, float* __restrict__ wts)
{
    const float ETAB[5] = {0.05f, 0.12f, 0.08f, 0.15f, 0.1f};
    __shared__ int   sums[NPTS][NC_];
    __shared__ float elas_s[NPTS];
    int b = blockIdx.x;
    int t = threadIdx.x;

    if (t < NPTS * NC_) {
        int pt = t / NC_, c = t - pt * NC_;
        int i = pt / 3, j = pt % 3;
        int yc = (i * (H_ - 1)) / 2;
        int xc = (j * (W_ - 1)) / 2;
        int y0 = yc - 2 < 0 ? 0 : yc - 2;
        int y1 = yc + 3 > H_ ? H_ : yc + 3;
        int x0 = xc - 2 < 0 ? 0 : xc - 2;
        int x1 = xc + 3 > W_ ? W_ : xc + 3;
        int s = 0;
        for (int y = y0; y < y1; ++y)
            for (int xx = x0; xx < x1; ++xx)
                s += masks[((size_t)b * NC_ + c) * HW_ + y * W_ + xx];
        sums[pt][c] = s;
    }
    __syncthreads();
    if (t < NPTS) {
        int best = -1, best_c = 0;
        #pragma unroll
        for (int c = 0; c < NC_; ++c) {
            int s = sums[t][c];
            if (s > best) { best = s; best_c = c; }  // strict >: first max (jnp.argmax)
        }
        elas_s[t] = ETAB[best_c];
    }
    __syncthreads();
    if (t < 24) {
        int tr = t / 12, r = t - tr * 12;       // tr=0 -> global (noise_g), 1 -> local
        const float* noise = (tr == 0) ? ng : nl;
        float disp[NPTS][2];
        #pragma unroll
        for (int k = 0; k < NPTS; ++k) {
            float e = elas_s[k];
            disp[k][0] = noise[((size_t)b * NPTS + k) * 2 + 0] * e;
            disp[k][1] = noise[((size_t)b * NPTS + k) * 2 + 1] * e;
        }
        #pragma unroll
        for (int c = 0; c < 2; ++c) {
            float nb = (disp[1][c] + disp[7][c] + disp[3][c] + disp[5][c]) * 0.25f;
            disp[4][c] = 0.8f * disp[4][c] + 0.2f * nb;
        }
        float a0 = 0.f, a1 = 0.f;
        #pragma unroll
        for (int k = 0; k < NPTS; ++k) {
            float d0 = (float)(k / 3 - 1) + disp[k][0];
            float d1 = (float)(k % 3 - 1) + disp[k][1];
            a0 += Linv.m[r][k] * d0;
            a1 += Linv.m[r][k] * d1;
        }
        float* wout = wts + ((size_t)tr * B_ + b) * 24;
        wout[r * 2 + 0] = a0;
        wout[r * 2 + 1] = a1;
    }
}

// ---------------- Shared coordinate machinery ------------------------------------------
// Computes clamped 32-bit tap offsets + validity-folded bilinear weights for one combo.
__device__ __forceinline__ void tps_coords(
    const float* __restrict__ wt, float px, float py, const float* __restrict__ u,
    int& o00, int& o01, int& o10, int& o11,
    float& w00, float& w01, float& w10, float& w11)
{
    float gx = wt[18] + px * wt[20] + py * wt[22];
    float gy = wt[19] + px * wt[21] + py * wt[23];
    #pragma unroll
    for (int k = 0; k < NPTS; ++k) {
        gx = fmaf(u[k], wt[k * 2 + 0], gx);
        gy = fmaf(u[k], wt[k * 2 + 1], gy);
    }
    const float sc = 0.5f * (float)(W_ - 1);
    float ix = fmaf(gx, sc, sc);               // (gx+1)*0.5*(W-1)
    float iy = fmaf(gy, sc, sc);               // H==W so same scale
    float x0f = floorf(ix), y0f = floorf(iy);
    float wx1 = ix - x0f, wx0 = 1.f - wx1;
    float wy1 = iy - y0f, wy0 = 1.f - wy1;
    int x0 = (int)x0f, y0 = (int)y0f;
    int x1 = x0 + 1,   y1 = y0 + 1;
    // validity folded into weights (unsigned trick: in [0,191])
    float fx0 = ((unsigned)x0 < (unsigned)W_) ? wx0 : 0.f;
    float fx1 = ((unsigned)x1 < (unsigned)W_) ? wx1 : 0.f;
    float fy0 = ((unsigned)y0 < (unsigned)H_) ? wy0 : 0.f;
    float fy1 = ((unsigned)y1 < (unsigned)H_) ? wy1 : 0.f;
    w00 = fy0 * fx0; w01 = fy0 * fx1; w10 = fy1 * fx0; w11 = fy1 * fx1;
    // clamped offsets: loads always in-bounds, zero weight kills OOB taps
    int xc0 = min(max(x0, 0), W_ - 1), xc1 = min(max(x1, 0), W_ - 1);
    int yc0 = min(max(y0, 0), H_ - 1), yc1 = min(max(y1, 0), H_ - 1);
    int r0 = yc0 * W_, r1 = yc1 * W_;
    o00 = r0 + xc0; o01 = r0 + xc1; o10 = r1 + xc0; o11 = r1 + xc1;
}

// ---------------- Kernel 3a: local transform (plain x taps), GROUP=4 ------------------
__global__ __launch_bounds__(256, 4) void warp_local_kernel(
    const float* __restrict__ x, const float* __restrict__ wts,
    float* __restrict__ out)
{
    int tx  = threadIdx.x;
    int wpx = blockIdx.x * 64 + (tx & 63);
    int h   = blockIdx.y * 4 + (tx >> 6);
    int p   = h * W_ + wpx;
    float px = -1.f + wpx * (2.f / (float)(W_ - 1));
    float py = -1.f + h   * (2.f / (float)(H_ - 1));

    float u[NPTS];
    #pragma unroll
    for (int k = 0; k < NPTS; ++k) {
        float dx = px - (float)(k / 3 - 1);
        float dy = py - (float)(k % 3 - 1);
        float d2 = dx * dx + dy * dy;
        u[k] = 0.5f * d2 * __logf(d2 + EPS_);
    }

    #pragma unroll
    for (int g = 0; g < CHUNK; g += 4) {
        int   o00[4], o01[4], o10[4], o11[4];
        float w00[4], w01[4], w10[4], w11[4];
        const float* xb[4];
        #pragma unroll
        for (int q = 0; q < 4; ++q) {
            int b = blockIdx.z * CHUNK + g + q;
            const float* wt = wts + ((size_t)(B_ + b)) * 24;  // local weights
            tps_coords(wt, px, py, u, o00[q], o01[q], o10[q], o11[q],
                       w00[q], w01[q], w10[q], w11[q]);
            xb[q] = x + (size_t)b * HW_;
        }
        float v00[4], v01[4], v10[4], v11[4];
        #pragma unroll
        for (int q = 0; q < 4; ++q) {
            v00[q] = xb[q][o00[q]];
            v01[q] = xb[q][o01[q]];
            v10[q] = xb[q][o10[q]];
            v11[q] = xb[q][o11[q]];
        }
        #pragma unroll
        for (int q = 0; q < 4; ++q) {
            int b = blockIdx.z * CHUNK + g + q;
            float val = w00[q] * v00[q] + w01[q] * v01[q] +
                        w10[q] * v10[q] + w11[q] * v11[q];
            __builtin_nontemporal_store(val, &out[((size_t)(B_ + b)) * HW_ + p]);
        }
    }
}

// ---------------- Kernel 3b: global transform (mixup fused at taps), GROUP=2 ----------
__global__ __launch_bounds__(256, 4) void warp_global_kernel(
    const float* __restrict__ x, const unsigned char* __restrict__ code,
    const float* __restrict__ wts, float* __restrict__ out,
    const float* __restrict__ lam_p, const int* __restrict__ perm)
{
    int tx  = threadIdx.x;
    int wpx = blockIdx.x * 64 + (tx & 63);
    int h   = blockIdx.y * 4 + (tx >> 6);
    int p   = h * W_ + wpx;
    float px = -1.f + wpx * (2.f / (float)(W_ - 1));
    float py = -1.f + h   * (2.f / (float)(H_ - 1));

    float u[NPTS];
    #pragma unroll
    for (int k = 0; k < NPTS; ++k) {
        float dx = px - (float)(k / 3 - 1);
        float dy = py - (float)(k % 3 - 1);
        float d2 = dx * dx + dy * dy;
        u[k] = 0.5f * d2 * __logf(d2 + EPS_);
    }

    float lam  = lam_p[0];
    float lam1 = 1.f - lam;

    #pragma unroll
    for (int g = 0; g < CHUNK; g += 2) {
        int   o00[2], o01[2], o10[2], o11[2];
        float w00[2], w01[2], w10[2], w11[2];
        const float* xb[2];
        const float* xpb[2];
        const unsigned char* cb[2];
        #pragma unroll
        for (int q = 0; q < 2; ++q) {
            int b = blockIdx.z * CHUNK + g + q;
            const float* wt = wts + (size_t)b * 24;            // global weights
            tps_coords(wt, px, py, u, o00[q], o01[q], o10[q], o11[q],
                       w00[q], w01[q], w10[q], w11[q]);
            int pb = perm[b];
            xb[q]  = x + (size_t)b * HW_;
            xpb[q] = x + (size_t)pb * HW_;
            cb[q]  = code + (size_t)b * HW_;
        }
        float xv00[2], xv01[2], xv10[2], xv11[2];
        float xp00[2], xp01[2], xp10[2], xp11[2];
        int   fg00[2], fg01[2], fg10[2], fg11[2];
        #pragma unroll
        for (int q = 0; q < 2; ++q) {
            xv00[q] = xb[q][o00[q]];  xp00[q] = xpb[q][o00[q]];  fg00[q] = cb[q][o00[q]];
            xv01[q] = xb[q][o01[q]];  xp01[q] = xpb[q][o01[q]];  fg01[q] = cb[q][o01[q]];
            xv10[q] = xb[q][o10[q]];  xp10[q] = xpb[q][o10[q]];  fg10[q] = cb[q][o10[q]];
            xv11[q] = xb[q][o11[q]];  xp11[q] = xpb[q][o11[q]];  fg11[q] = cb[q][o11[q]];
        }
        #pragma unroll
        for (int q = 0; q < 2; ++q) {
            int b = blockIdx.z * CHUNK + g + q;
            // mixed = xv*(bg + fg*lam) + xpv*(fg*(1-lam)), bg = (fg==0)
            float f0 = (float)fg00[q], f1 = (float)fg01[q];
            float f2 = (float)fg10[q], f3 = (float)fg11[q];
            float a0 = (f0 == 0.f ? 1.f : 0.f) + f0 * lam;
            float a1 = (f1 == 0.f ? 1.f : 0.f) + f1 * lam;
            float a2 = (f2 == 0.f ? 1.f : 0.f) + f2 * lam;
            float a3 = (f3 == 0.f ? 1.f : 0.f) + f3 * lam;
            float v00 = a0 * xv00[q] + (f0 * lam1) * xp00[q];
            float v01 = a1 * xv01[q] + (f1 * lam1) * xp01[q];
            float v10 = a2 * xv10[q] + (f2 * lam1) * xp10[q];
            float v11 = a3 * xv11[q] + (f3 * lam1) * xp11[q];
            float val = w00[q] * v00 + w01[q] * v01 + w10[q] * v10 + w11[q] * v11;
            __builtin_nontemporal_store(val, &out[(size_t)b * HW_ + p]);
        }
    }
}

// ---------------- Host: build constant L^-1 (first 9 columns) in double ----------------
static void build_linv(LinvT* out)
{
    double srcp[NPTS][2];
    for (int k = 0; k < NPTS; ++k) {
        srcp[k][0] = (double)(k / 3) - 1.0;
        srcp[k][1] = (double)(k % 3) - 1.0;
    }
    double A[12][24];
    for (int r = 0; r < 12; ++r)
        for (int c = 0; c < 24; ++c) A[r][c] = 0.0;
    for (int i = 0; i < NPTS; ++i) {
        for (int j = 0; j < NPTS; ++j) {
            double dx = srcp[i][0] - srcp[j][0];
            double dy = srcp[i][1] - srcp[j][1];
            double d2 = dx * dx + dy * dy;
            A[i][j] = 0.5 * d2 * log(d2 + 1e-8);
        }
        A[i][9]  = 1.0; A[i][10] = srcp[i][0]; A[i][11] = srcp[i][1];
        A[9][i]  = 1.0; A[10][i] = srcp[i][0]; A[11][i] = srcp[i][1];
    }
    for (int r = 0; r < 12; ++r) A[r][12 + r] = 1.0;
    for (int col = 0; col < 12; ++col) {
        int piv = col; double mx = fabs(A[col][col]);
        for (int r = col + 1; r < 12; ++r)
            if (fabs(A[r][col]) > mx) { mx = fabs(A[r][col]); piv = r; }
        if (piv != col)
            for (int c = 0; c < 24; ++c) { double tmp = A[col][c]; A[col][c] = A[piv][c]; A[piv][c] = tmp; }
        double d = A[col][col];
        for (int c = 0; c < 24; ++c) A[col][c] /= d;
        for (int r = 0; r < 12; ++r) {
            if (r == col) continue;
            double f = A[r][col];
            if (f != 0.0)
                for (int c = 0; c < 24; ++c) A[r][c] -= f * A[col][c];
        }
    }
    for (int r = 0; r < 12; ++r)
        for (int k = 0; k < NPTS; ++k)
            out->m[r][k] = (float)A[r][12 + k];
}

extern "C" void kernel_launch(void* const* d_in, const int* in_sizes, int n_in,
                              void* d_out, int out_size, void* d_ws, size_t ws_size,
                              hipStream_t stream)
{
    (void)in_sizes; (void)n_in; (void)out_size; (void)ws_size;
    const float* x     = (const float*)d_in[0];
    const int*   masks = (const int*)d_in[1];
    const float* lam   = (const float*)d_in[2];
    const int*   perm  = (const int*)d_in[3];
    const float* ng    = (const float*)d_in[4];
    const float* nl    = (const float*)d_in[5];
    float* out = (float*)d_out;

    char* ws = (char*)d_ws;
    float*        wts  = (float*)ws;                      // 2*128*24*4 = 24576 B
    unsigned int* code = (unsigned int*)(ws + 32768);     // B*HW bytes = 4.7 MB

    LinvT Linv;
    build_linv(&Linv);

    int total4 = B_ * HW_ / 4;
    code_kernel<<<(total4 + 255) / 256, 256, 0, stream>>>(masks, code);
    prep_kernel<<<B_, 64, 0, stream>>>(masks, ng, nl, Linv, wts);

    dim3 wgrid(W_ / 64, H_ / 4, B_ / CHUNK);
    warp_global_kernel<<<wgrid, 256, 0, stream>>>(
        x, (const unsigned char*)code, wts, out, lam, perm);
    warp_local_kernel<<<wgrid, 256, 0, stream>>>(x, wts, out);
}

// Round 6
// 61.045 us; speedup vs baseline: 1.2617x; 1.2617x over previous
//
#include <hip/hip_runtime.h>
#include <math.h>

#define B_   128
#define H_   192
#define W_   192
#define NC_  5
#define HW_  (H_*W_)
#define NPTS 9
#define EPS_ 1e-8f
#define CHUNK 16   // combos per warp-kernel block (blockIdx.z uniform in transform t)

typedef int   vint4   __attribute__((ext_vector_type(4)));
typedef float vfloat4 __attribute__((ext_vector_type(4)));
typedef float vfloat2 __attribute__((ext_vector_type(2)));

struct LinvT { float m[12][NPTS]; };

// ---------------- Kernel 1: class_aware_mixup (one 151 MB streaming pass) -------------
__global__ __launch_bounds__(256) void mixup_kernel(
    const float* __restrict__ x, const int* __restrict__ masks,
    const float* __restrict__ lam_p, const int* __restrict__ perm,
    float* __restrict__ mixed)
{
    int idx = blockIdx.x * 256 + threadIdx.x;
    const int total4 = B_ * HW_ / 4;
    if (idx >= total4) return;
    float lam = lam_p[0];
    int b  = idx / (HW_ / 4);
    int p4 = (idx - b * (HW_ / 4)) * 4;
    const vfloat4 xv = *reinterpret_cast<const vfloat4*>(x + (size_t)b * HW_ + p4);
    int pb = perm[b];
    const vfloat4 xp = *reinterpret_cast<const vfloat4*>(x + (size_t)pb * HW_ + p4);

    vint4 ma[NC_];
    #pragma unroll
    for (int c = 0; c < NC_; ++c) {
        const vint4* mp = reinterpret_cast<const vint4*>(masks + ((size_t)b * NC_ + c) * HW_ + p4);
        ma[c] = __builtin_nontemporal_load(mp);   // streamed once, evict-first
    }
    vfloat4 outv;
    #pragma unroll
    for (int l = 0; l < 4; ++l) {
        int s = 0, fg = 0;
        #pragma unroll
        for (int c = 0; c < NC_; ++c) { int m = ma[c][l]; s += m; fg += (m == 1); }
        float bg = (s == 0) ? 1.f : 0.f;
        outv[l] = bg * xv[l] + (float)fg * (lam * xv[l] + (1.f - lam) * xp[l]);
    }
    *reinterpret_cast<vfloat4*>(mixed + (size_t)b * HW_ + p4) = outv;
}

// ---------------- Kernel 2: point_elasticity + TPS solve fused (per-batch block) ------
__global__ void prep_kernel(const int* __restrict__ masks,
                            const float* __restrict__ ng,
                            const float* __restrict__ nl,
                            LinvT Linv, float* __restrict__ wts)
{
    const float ETAB[5] = {0.05f, 0.12f, 0.08f, 0.15f, 0.1f};
    __shared__ int   sums[NPTS][NC_];
    __shared__ float elas_s[NPTS];
    int b = blockIdx.x;
    int t = threadIdx.x;

    if (t < NPTS * NC_) {
        int pt = t / NC_, c = t - pt * NC_;
        int i = pt / 3, j = pt % 3;
        int yc = (i * (H_ - 1)) / 2;
        int xc = (j * (W_ - 1)) / 2;
        int y0 = yc - 2 < 0 ? 0 : yc - 2;
        int y1 = yc + 3 > H_ ? H_ : yc + 3;
        int x0 = xc - 2 < 0 ? 0 : xc - 2;
        int x1 = xc + 3 > W_ ? W_ : xc + 3;
        int s = 0;
        for (int y = y0; y < y1; ++y)
            for (int xx = x0; xx < x1; ++xx)
                s += masks[((size_t)b * NC_ + c) * HW_ + y * W_ + xx];
        sums[pt][c] = s;
    }
    __syncthreads();
    if (t < NPTS) {
        int best = -1, best_c = 0;
        #pragma unroll
        for (int c = 0; c < NC_; ++c) {
            int s = sums[t][c];
            if (s > best) { best = s; best_c = c; }  // strict >: first max (jnp.argmax)
        }
        elas_s[t] = ETAB[best_c];
    }
    __syncthreads();
    if (t < 24) {
        int tr = t / 12, r = t - tr * 12;       // tr=0 -> global (noise_g), 1 -> local
        const float* noise = (tr == 0) ? ng : nl;
        float disp[NPTS][2];
        #pragma unroll
        for (int k = 0; k < NPTS; ++k) {
            float e = elas_s[k];
            disp[k][0] = noise[((size_t)b * NPTS + k) * 2 + 0] * e;
            disp[k][1] = noise[((size_t)b * NPTS + k) * 2 + 1] * e;
        }
        #pragma unroll
        for (int c = 0; c < 2; ++c) {
            float nb = (disp[1][c] + disp[7][c] + disp[3][c] + disp[5][c]) * 0.25f;
            disp[4][c] = 0.8f * disp[4][c] + 0.2f * nb;
        }
        float a0 = 0.f, a1 = 0.f;
        #pragma unroll
        for (int k = 0; k < NPTS; ++k) {
            float d0 = (float)(k / 3 - 1) + disp[k][0];
            float d1 = (float)(k % 3 - 1) + disp[k][1];
            a0 += Linv.m[r][k] * d0;
            a1 += Linv.m[r][k] * d1;
        }
        float* wout = wts + ((size_t)tr * B_ + b) * 24;
        wout[r * 2 + 0] = a0;
        wout[r * 2 + 1] = a1;
    }
}

// ---------------- Coordinate machinery: packed-f32 dot product + cheap tail -----------
// wt2[0..8] = kernel weight pairs (wx,wy); wt2[9..11] = affine rows (1, px, py).
__device__ __forceinline__ void tps_coords_pk(
    const vfloat2* __restrict__ wt2, float px, float py, const float* __restrict__ u,
    int& o00, int& o01, int& o10, int& o11,
    float& w00, float& w01, float& w10, float& w11)
{
    vfloat2 g = wt2[9];
    g = __builtin_elementwise_fma((vfloat2){px, px}, wt2[10], g);
    g = __builtin_elementwise_fma((vfloat2){py, py}, wt2[11], g);
    #pragma unroll
    for (int k = 0; k < NPTS; ++k)
        g = __builtin_elementwise_fma((vfloat2){u[k], u[k]}, wt2[k], g);

    const float sc = 0.5f * (float)(W_ - 1);
    float ix = fmaf(g.x, sc, sc);              // (gx+1)*0.5*(W-1); H==W
    float iy = fmaf(g.y, sc, sc);
    float x0f = floorf(ix), y0f = floorf(iy);
    float wx1 = ix - x0f, wx0 = 1.f - wx1;
    float wy1 = iy - y0f, wy0 = 1.f - wy1;
    int x0 = (int)x0f, y0 = (int)y0f;
    // validity folded into weights
    float fx0 = ((unsigned)x0 < 192u)       ? wx0 : 0.f;
    float fx1 = ((unsigned)(x0 + 1) < 192u) ? wx1 : 0.f;
    float fy0 = ((unsigned)y0 < 192u)       ? wy0 : 0.f;
    float fy1 = ((unsigned)(y0 + 1) < 192u) ? wy1 : 0.f;
    w00 = fy0 * fx0; w01 = fy0 * fx1; w10 = fy1 * fx0; w11 = fy1 * fx1;
    // single flat-offset clamp per tap: keeps load in-bounds of this image;
    // value is irrelevant when the corresponding weight is 0.
    int o = y0 * W_ + x0;
    o00 = min(max(o, 0), HW_ - 1);
    o01 = min(max(o + 1, 0), HW_ - 1);
    o10 = min(max(o + W_, 0), HW_ - 1);
    o11 = min(max(o + W_ + 1, 0), HW_ - 1);
}

// ---------------- Kernel 3: unified TPS warp + bilinear, 4-combo ILP groups -----------
__global__ __launch_bounds__(256, 2) void warp_kernel(
    const float* __restrict__ x, const float* __restrict__ mixed,
    const float* __restrict__ wts, float* __restrict__ out)
{
    int tx  = threadIdx.x;
    int wpx = blockIdx.x * 64 + (tx & 63);    // grid.x = W/64 = 3
    int h   = blockIdx.y * 4 + (tx >> 6);     // grid.y = H/4 = 48
    int p   = h * W_ + wpx;
    float px = -1.f + wpx * (2.f / (float)(W_ - 1));
    float py = -1.f + h   * (2.f / (float)(H_ - 1));

    float u[NPTS];
    #pragma unroll
    for (int k = 0; k < NPTS; ++k) {
        float dx = px - (float)(k / 3 - 1);
        float dy = py - (float)(k % 3 - 1);
        float d2 = dx * dx + dy * dy;
        u[k] = 0.5f * d2 * __logf(d2 + EPS_);
    }

    const vfloat2* wt2base = reinterpret_cast<const vfloat2*>(wts);

    #pragma unroll
    for (int g4 = 0; g4 < CHUNK; g4 += 4) {
        int   o00[4], o01[4], o10[4], o11[4];
        float w00[4], w01[4], w10[4], w11[4];
        const float* src[4];
        #pragma unroll
        for (int q = 0; q < 4; ++q) {
            int combo = blockIdx.z * CHUNK + g4 + q;   // block-uniform
            int t = combo >> 7;
            int b = combo & (B_ - 1);
            src[q] = (t == 0 ? mixed : x) + (size_t)b * HW_;
            tps_coords_pk(wt2base + (size_t)combo * 12, px, py, u,
                          o00[q], o01[q], o10[q], o11[q],
                          w00[q], w01[q], w10[q], w11[q]);
        }
        float v00[4], v01[4], v10[4], v11[4];
        #pragma unroll
        for (int q = 0; q < 4; ++q) {
            v00[q] = src[q][o00[q]];
            v01[q] = src[q][o01[q]];
            v10[q] = src[q][o10[q]];
            v11[q] = src[q][o11[q]];
        }
        #pragma unroll
        for (int q = 0; q < 4; ++q) {
            int combo = blockIdx.z * CHUNK + g4 + q;
            float val = w00[q] * v00[q] + w01[q] * v01[q] +
                        w10[q] * v10[q] + w11[q] * v11[q];
            __builtin_nontemporal_store(val, &out[(size_t)combo * HW_ + p]);
        }
    }
}

// ---------------- Host: build constant L^-1 (first 9 columns) in double ----------------
static void build_linv(LinvT* out)
{
    double srcp[NPTS][2];
    for (int k = 0; k < NPTS; ++k) {
        srcp[k][0] = (double)(k / 3) - 1.0;
        srcp[k][1] = (double)(k % 3) - 1.0;
    }
    double A[12][24];
    for (int r = 0; r < 12; ++r)
        for (int c = 0; c < 24; ++c) A[r][c] = 0.0;
    for (int i = 0; i < NPTS; ++i) {
        for (int j = 0; j < NPTS; ++j) {
            double dx = srcp[i][0] - srcp[j][0];
            double dy = srcp[i][1] - srcp[j][1];
            double d2 = dx * dx + dy * dy;
            A[i][j] = 0.5 * d2 * log(d2 + 1e-8);
        }
        A[i][9]  = 1.0; A[i][10] = srcp[i][0]; A[i][11] = srcp[i][1];
        A[9][i]  = 1.0; A[10][i] = srcp[i][0]; A[11][i] = srcp[i][1];
    }
    for (int r = 0; r < 12; ++r) A[r][12 + r] = 1.0;
    for (int col = 0; col < 12; ++col) {
        int piv = col; double mx = fabs(A[col][col]);
        for (int r = col + 1; r < 12; ++r)
            if (fabs(A[r][col]) > mx) { mx = fabs(A[r][col]); piv = r; }
        if (piv != col)
            for (int c = 0; c < 24; ++c) { double tmp = A[col][c]; A[col][c] = A[piv][c]; A[piv][c] = tmp; }
        double d = A[col][col];
        for (int c = 0; c < 24; ++c) A[col][c] /= d;
        for (int r = 0; r < 12; ++r) {
            if (r == col) continue;
            double f = A[r][col];
            if (f != 0.0)
                for (int c = 0; c < 24; ++c) A[r][c] -= f * A[col][c];
        }
    }
    for (int r = 0; r < 12; ++r)
        for (int k = 0; k < NPTS; ++k)
            out->m[r][k] = (float)A[r][12 + k];
}

extern "C" void kernel_launch(void* const* d_in, const int* in_sizes, int n_in,
                              void* d_out, int out_size, void* d_ws, size_t ws_size,
                              hipStream_t stream)
{
    (void)in_sizes; (void)n_in; (void)out_size; (void)ws_size;
    const float* x     = (const float*)d_in[0];
    const int*   masks = (const int*)d_in[1];
    const float* lam   = (const float*)d_in[2];
    const int*   perm  = (const int*)d_in[3];
    const float* ng    = (const float*)d_in[4];
    const float* nl    = (const float*)d_in[5];
    float* out = (float*)d_out;

    char* ws = (char*)d_ws;
    float* wts   = (float*)ws;              // 2*128*24*4 = 24576 B
    float* mixed = (float*)(ws + 32768);    // B*HW*4    = 18.9 MB

    LinvT Linv;
    build_linv(&Linv);

    int total4 = B_ * HW_ / 4;
    mixup_kernel<<<(total4 + 255) / 256, 256, 0, stream>>>(x, masks, lam, perm, mixed);
    prep_kernel<<<B_, 64, 0, stream>>>(masks, ng, nl, Linv, wts);

    dim3 wgrid(W_ / 64, H_ / 4, (2 * B_) / CHUNK);
    warp_kernel<<<wgrid, 256, 0, stream>>>(x, mixed, wts, out);
}